// Round 5
// baseline (120.268 us; speedup 1.0000x reference)
//
#include <hip/hip_runtime.h>
#include <hip/hip_bf16.h>
#include <math.h>

// Problem constants (from reference): path_fea (131072, 64, 1, 1, 2) fp32
#define B_ROWS   131072
#define D_DIM    128          // 64 * 2
#define P_SAMP   16
#define G_GROUPS 8192         // B / P
#define T128     64           // 128-row tiles per dim (G / 128)
#define NTRI2    2080         // T128*(T128+1)/2 triangular block-tiles
#define K1_BLOCKS (G_GROUPS / 4)

typedef __bf16 bf16x8  __attribute__((ext_vector_type(8)));
typedef float  floatx4 __attribute__((ext_vector_type(4)));
typedef unsigned short u16x8 __attribute__((ext_vector_type(8)));

// Fragment-friendly center layout (written by K1, read by K2):
//   granule index = (row>>4)*256 + gg*16 + (row&15),  gg = k-octet 0..15
//   each granule = 8 bf16 (16 B). A 128-row panel is one CONTIGUOUS 32 KB
//   chunk (granules [row0*16, row0*16+2048)) -> coalesced staging + LDS.

__device__ __forceinline__ float wave_red64(float v) {
    #pragma unroll
    for (int off = 32; off > 0; off >>= 1) v += __shfl_xor(v, off, 64);
    return v;
}

// ---------------------------------------------------------------------------
// K1: per-group centers (bf16, fragment layout) + |center|^2 + intra hinge.
// One wave per group. Lane t: dims [4*(t&31), +4) of samples (t>>5)+2l.
// All global loads are 1KB-contiguous wave-loads (float4).
// ---------------------------------------------------------------------------
__global__ __launch_bounds__(256) void k_center_intra(
    const float* __restrict__ x,            // [B, 128]
    uint2* __restrict__ cfrag,               // [G*32] 8B halves of granules
    float* __restrict__ sq,                  // [G]
    float* __restrict__ partial,             // [K1_BLOCKS] intra partials
    float* __restrict__ acc)                 // acc[0] zeroed here
{
    const int wave = threadIdx.x >> 6;
    const int lane = threadIdx.x & 63;
    const int half = lane >> 5;      // sample parity this lane owns
    const int c    = lane & 31;      // dim-quad index (4 dims per lane)
    const int g    = blockIdx.x * 4 + wave;

    if (blockIdx.x == 0 && threadIdx.x == 0) acc[0] = 0.f;   // K2's accumulator

    // sample s = 2*l + half, dims 4c..4c+3
    const float* base = x + (size_t)g * (P_SAMP * D_DIM) + half * D_DIM + c * 4;

    floatx4 v[8];
    #pragma unroll
    for (int l = 0; l < 8; ++l)
        v[l] = *(const floatx4*)(base + l * (2 * D_DIM));

    // center: sum my half's 8 samples, then add the other half's
    floatx4 cs = v[0];
    #pragma unroll
    for (int l = 1; l < 8; ++l) cs += v[l];
    #pragma unroll
    for (int k = 0; k < 4; ++k) cs[k] += __shfl_xor(cs[k], 32, 64);
    floatx4 ctr = cs * (1.0f / P_SAMP);

    // 9 parallel partial sums: 8 sample dists + center sq-norm
    float p[9];
    #pragma unroll
    for (int l = 0; l < 8; ++l) {
        floatx4 d = v[l] - ctr;
        p[l] = d[0]*d[0] + d[1]*d[1] + d[2]*d[2] + d[3]*d[3];
    }
    p[8] = ctr[0]*ctr[0] + ctr[1]*ctr[1] + ctr[2]*ctr[2] + ctr[3]*ctr[3];

    #pragma unroll
    for (int off = 16; off > 0; off >>= 1) {
        #pragma unroll
        for (int s = 0; s < 9; ++s) p[s] += __shfl_xor(p[s], off, 64);
    }
    // p[l] = full 128-dim dist^2 of sample 2l+half; p[8] = |center|^2

    // store bf16 center into fragment layout: lane c covers dims 4c..4c+3 =
    // granule gg=c>>1, half-granule c&1. 8 B per lane, half 0 only.
    if (half == 0) {
        unsigned int b0 = __builtin_bit_cast(unsigned short, (__bf16)ctr[0]);
        unsigned int b1 = __builtin_bit_cast(unsigned short, (__bf16)ctr[1]);
        unsigned int b2 = __builtin_bit_cast(unsigned short, (__bf16)ctr[2]);
        unsigned int b3 = __builtin_bit_cast(unsigned short, (__bf16)ctr[3]);
        uint2 pk;
        pk.x = (b1 << 16) | b0;
        pk.y = (b3 << 16) | b2;
        const int gran = (g >> 4) * 256 + (c >> 1) * 16 + (g & 15);
        cfrag[gran * 2 + (c & 1)] = pk;
    }
    if (lane == 0) sq[g] = p[8];

    // intra hinge for my half's 8 samples, combine halves
    float isum = 0.f;
    #pragma unroll
    for (int l = 0; l < 8; ++l) {
        float d = sqrtf(p[l]);
        float t = fmaxf(d - 0.1f, 0.f);
        isum += t * t;
    }
    isum += __shfl_xor(isum, 32, 64);

    __shared__ float sh[4];
    if (lane == 0) sh[wave] = isum;
    __syncthreads();
    if (threadIdx.x == 0)
        partial[blockIdx.x] = sh[0] + sh[1] + sh[2] + sh[3];
}

// ---------------------------------------------------------------------------
// K2: inter hinge. One BLOCK per 128x128 triangular tile; 4 waves take the
// four 64x64 quadrants. A/B panels are contiguous 32 KB chunks of the
// fragment-ordered buffer -> staged to LDS with coalesced 1 KB wave-loads
// and linear ds_write_b128 (conflict-free). Fragment reads are contiguous
// ds_read_b128 (conflict-free). L2 traffic halves vs wave-private tiles.
// Diagonal blocks skip the strictly-lower quadrant after the barrier.
// ---------------------------------------------------------------------------
__global__ __launch_bounds__(256) void k_inter(
    const u16x8* __restrict__ cfrag,         // granule array (16 B each)
    const float* __restrict__ sq,            // [G]
    float* __restrict__ acc)                 // acc[0] = inter hinge sum
{
    __shared__ u16x8 smem[4096];   // [0,2048)=A panel, [2048,4096)=B; 64 KB

    // triangular decode over T128=64: off(i) = 64i - i(i-1)/2
    const int bid = blockIdx.x;
    float sf = sqrtf(64.5f * 64.5f - 2.0f * (float)bid);
    int ti = (int)(64.5f - sf);
    if (ti < 0) ti = 0;
    if (ti > T128 - 1) ti = T128 - 1;
    #define TRI_OFF(i) ((i) * T128 - (((i) * ((i) - 1)) >> 1))
    while (ti > 0 && TRI_OFF(ti) > bid) --ti;
    while (ti < T128 - 1 && TRI_OFF(ti + 1) <= bid) ++ti;
    const int tj = ti + (bid - TRI_OFF(ti));
    #undef TRI_OFF

    // stage A (rows ti*128..+128) and B (rows tj*128..+128): contiguous
    const int t = threadIdx.x;
    const size_t abase = (size_t)ti * 2048;   // granule index of A chunk
    const size_t bbase = (size_t)tj * 2048;
    #pragma unroll
    for (int it = 0; it < 8; ++it) {
        const int idx = t + it * 256;         // 0..2047
        smem[idx]        = cfrag[abase + idx];
        smem[idx + 2048] = cfrag[bbase + idx];
    }
    __syncthreads();

    const int wave = t >> 6;
    const int lane = t & 63;
    const int wr   = wave >> 1;    // 0..1: which 64-row half of i
    const int wc   = wave & 1;     // 0..1: which 64-col half of j
    const int lrow = lane & 15;
    const int quad = lane >> 4;

    const bool bdiag = (ti == tj);
    if (bdiag && wr > wc) return;            // strictly-lower quadrant: i > j always

    const int i0 = ti * 128 + wr * 64;
    const int j0 = tj * 128 + wc * 64;

    // epilogue sq values (L2 hits, retire while MFMAs run)
    floatx4 sqi[4];
    float   sqj[4];
    #pragma unroll
    for (int mt = 0; mt < 4; ++mt)
        sqi[mt] = *(const floatx4*)(sq + i0 + mt * 16 + quad * 4);
    #pragma unroll
    for (int nt = 0; nt < 4; ++nt)
        sqj[nt] = sq[j0 + nt * 16 + lrow];

    floatx4 c4[4][4] = {};   // 16 accumulator tiles of 16x16

    #pragma unroll
    for (int ks = 0; ks < 4; ++ks) {               // K = 128, 32 per MFMA
        const int go = (ks * 4 + quad) * 16 + lrow;  // granule offset in panel
        bf16x8 a[4], b[4];
        #pragma unroll
        for (int mt = 0; mt < 4; ++mt)
            a[mt] = __builtin_bit_cast(bf16x8, smem[(wr * 4 + mt) * 256 + go]);
        #pragma unroll
        for (int nt = 0; nt < 4; ++nt)
            b[nt] = __builtin_bit_cast(bf16x8, smem[2048 + (wc * 4 + nt) * 256 + go]);
        #pragma unroll
        for (int mt = 0; mt < 4; ++mt)
            #pragma unroll
            for (int nt = 0; nt < 4; ++nt)
                c4[mt][nt] = __builtin_amdgcn_mfma_f32_16x16x32_bf16(
                                a[mt], b[nt], c4[mt][nt], 0, 0, 0);
    }

    // Epilogue: d2 = sq[i]+sq[j]-2*gram; hinge nonzero only when d2 < 1.
    const bool qdiag = (bdiag && wr == wc);
    float hsum = 0.f;
    #pragma unroll
    for (int mt = 0; mt < 4; ++mt) {
        #pragma unroll
        for (int nt = 0; nt < 4; ++nt) {
            const int ib = i0 + mt * 16 + quad * 4;
            const int j  = j0 + nt * 16 + lrow;
            #pragma unroll
            for (int r = 0; r < 4; ++r) {
                if (qdiag && j <= ib + r) continue;
                float d2 = sqi[mt][r] + sqj[nt] - 2.0f * c4[mt][nt][r];
                if (d2 < 1.0f) {                       // rare path
                    float d = sqrtf(fmaxf(d2, 0.f));
                    float tt = 1.0f - d;
                    hsum += tt * tt;
                }
            }
        }
    }
    if (__ballot(hsum != 0.f)) {
        hsum = wave_red64(hsum);
        if (lane == 0) atomicAdd(acc, hsum);
    }
}

// ---------------------------------------------------------------------------
// K3: reduce K1 partials, finalize both outputs.
// ---------------------------------------------------------------------------
__global__ __launch_bounds__(256) void k_final(
    const float* __restrict__ acc,
    const float* __restrict__ partial,
    float* __restrict__ out)
{
    __shared__ float sh[4];
    float s = 0.f;
    for (int i = threadIdx.x; i < K1_BLOCKS; i += 256) s += partial[i];
    s = wave_red64(s);
    const int wave = threadIdx.x >> 6;
    const int lane = threadIdx.x & 63;
    if (lane == 0) sh[wave] = s;
    __syncthreads();
    if (threadIdx.x == 0) {
        const float n_pairs = (float)G_GROUPS * (float)(G_GROUPS - 1) * 0.5f;
        out[0] = acc[0] / n_pairs;                                 // inter
        out[1] = (sh[0] + sh[1] + sh[2] + sh[3]) / (float)B_ROWS;  // intra
    }
}

extern "C" void kernel_launch(void* const* d_in, const int* in_sizes, int n_in,
                              void* d_out, int out_size, void* d_ws, size_t ws_size,
                              hipStream_t stream) {
    const float* x = (const float*)d_in[0];
    float* out = (float*)d_out;

    // workspace layout
    float* acc     = (float*)d_ws;                          // 4 B
    float* partial = (float*)((char*)d_ws + 256);           // 8 KB
    float* sq      = (float*)((char*)d_ws + 16384);         // 32 KB
    uint2* cfrag   = (uint2*)((char*)d_ws + 65536);         // 2 MB bf16 centers

    k_center_intra<<<K1_BLOCKS, 256, 0, stream>>>(x, cfrag, sq, partial, acc);

    k_inter<<<NTRI2, 256, 0, stream>>>((const u16x8*)cfrag, sq, acc);

    k_final<<<1, 256, 0, stream>>>(acc, partial, out);
}

// Round 6
// 117.507 us; speedup vs baseline: 1.0235x; 1.0235x over previous
//
#include <hip/hip_runtime.h>
#include <hip/hip_bf16.h>
#include <math.h>

// Problem constants (from reference): path_fea (131072, 64, 1, 1, 2) fp32
#define B_ROWS   131072
#define D_DIM    128          // 64 * 2
#define P_SAMP   16
#define G_GROUPS 8192         // B / P
#define T128     64           // 128-row tiles per dim (G / 128)
#define CHUNK    4            // j-tiles swept per block
#define NCHUNK   544          // sum over ti of ceil((64-ti)/4)
#define K1_BLOCKS (G_GROUPS / 4)

typedef __bf16 bf16x8  __attribute__((ext_vector_type(8)));
typedef float  floatx4 __attribute__((ext_vector_type(4)));
typedef unsigned short u16x8 __attribute__((ext_vector_type(8)));

// Fragment-ordered center layout (written by K1, read by K2):
//   granule index = (row>>4)*256 + gg*16 + (row&15),  gg = k-octet 0..15
//   each granule = 8 bf16 (16 B). A 128-row panel = one CONTIGUOUS 32 KB
//   chunk -> coalesced staging / 1 KB contiguous wave fragment loads.

__device__ __forceinline__ float wave_red64(float v) {
    #pragma unroll
    for (int off = 32; off > 0; off >>= 1) v += __shfl_xor(v, off, 64);
    return v;
}

// ---------------------------------------------------------------------------
// K1: per-group centers (bf16, fragment layout) + |center|^2 + intra hinge.
// One wave per group; all global loads are 1KB-contiguous wave-loads.
// ---------------------------------------------------------------------------
__global__ __launch_bounds__(256) void k_center_intra(
    const float* __restrict__ x,            // [B, 128]
    uint2* __restrict__ cfrag,               // [G*32] 8B halves of granules
    float* __restrict__ sq,                  // [G]
    float* __restrict__ partial,             // [K1_BLOCKS] intra partials
    float* __restrict__ acc)                 // acc[0] zeroed here
{
    const int wave = threadIdx.x >> 6;
    const int lane = threadIdx.x & 63;
    const int half = lane >> 5;      // sample parity this lane owns
    const int c    = lane & 31;      // dim-quad index (4 dims per lane)
    const int g    = blockIdx.x * 4 + wave;

    if (blockIdx.x == 0 && threadIdx.x == 0) acc[0] = 0.f;   // K2's accumulator

    // sample s = 2*l + half, dims 4c..4c+3
    const float* base = x + (size_t)g * (P_SAMP * D_DIM) + half * D_DIM + c * 4;

    floatx4 v[8];
    #pragma unroll
    for (int l = 0; l < 8; ++l)
        v[l] = *(const floatx4*)(base + l * (2 * D_DIM));

    floatx4 cs = v[0];
    #pragma unroll
    for (int l = 1; l < 8; ++l) cs += v[l];
    #pragma unroll
    for (int k = 0; k < 4; ++k) cs[k] += __shfl_xor(cs[k], 32, 64);
    floatx4 ctr = cs * (1.0f / P_SAMP);

    // 9 parallel partial sums: 8 sample dists + center sq-norm
    float p[9];
    #pragma unroll
    for (int l = 0; l < 8; ++l) {
        floatx4 d = v[l] - ctr;
        p[l] = d[0]*d[0] + d[1]*d[1] + d[2]*d[2] + d[3]*d[3];
    }
    p[8] = ctr[0]*ctr[0] + ctr[1]*ctr[1] + ctr[2]*ctr[2] + ctr[3]*ctr[3];

    #pragma unroll
    for (int off = 16; off > 0; off >>= 1) {
        #pragma unroll
        for (int s = 0; s < 9; ++s) p[s] += __shfl_xor(p[s], off, 64);
    }

    // store bf16 center into fragment layout (8 B per lane, half 0 only)
    if (half == 0) {
        unsigned int b0 = __builtin_bit_cast(unsigned short, (__bf16)ctr[0]);
        unsigned int b1 = __builtin_bit_cast(unsigned short, (__bf16)ctr[1]);
        unsigned int b2 = __builtin_bit_cast(unsigned short, (__bf16)ctr[2]);
        unsigned int b3 = __builtin_bit_cast(unsigned short, (__bf16)ctr[3]);
        uint2 pk;
        pk.x = (b1 << 16) | b0;
        pk.y = (b3 << 16) | b2;
        const int gran = (g >> 4) * 256 + (c >> 1) * 16 + (g & 15);
        cfrag[gran * 2 + (c & 1)] = pk;
    }
    if (lane == 0) sq[g] = p[8];

    float isum = 0.f;
    #pragma unroll
    for (int l = 0; l < 8; ++l) {
        float d = sqrtf(p[l]);
        float t = fmaxf(d - 0.1f, 0.f);
        isum += t * t;
    }
    isum += __shfl_xor(isum, 32, 64);

    __shared__ float sh[4];
    if (lane == 0) sh[wave] = isum;
    __syncthreads();
    if (threadIdx.x == 0)
        partial[blockIdx.x] = sh[0] + sh[1] + sh[2] + sh[3];
}

// ---------------------------------------------------------------------------
// K2: inter hinge, chunked row-strips. Block = (ti, chunk of <=4 j-tiles).
// A panel (128 rows, contiguous 32 KB) staged to LDS ONCE; the j-sweep then
// streams B fragments direct-to-register (contiguous 1 KB wave-loads,
// k-batch double-buffered) with NO barriers — B-load latency hides behind
// the previous tile's MFMAs and 3 waves/SIMD occupancy.
// L2 traffic: 17 MB (A) + 67 MB (B) vs 264 MB for wave-private tiles.
// ---------------------------------------------------------------------------
__global__ __launch_bounds__(256, 3) void k_inter(
    const u16x8* __restrict__ cfrag,         // granule array (16 B each)
    const float* __restrict__ sq,            // [G]
    float* __restrict__ acc)                 // acc[0] = inter hinge sum
{
    __shared__ u16x8 smemA[2048];   // 32 KB: A panel, fragment order

    // decode blockIdx.x -> (ti, chunk index within strip)
    int rem = blockIdx.x;
    int ti = 0;
    for (;;) {
        int n = (T128 - ti + CHUNK - 1) / CHUNK;
        if (rem < n) break;
        rem -= n;
        ++ti;
    }
    const int tj0   = ti + rem * CHUNK;
    const int tjend = min(tj0 + CHUNK, T128);

    // stage A panel (rows ti*128..+128): one contiguous 32 KB chunk
    const int t = threadIdx.x;
    const size_t abase = (size_t)ti * 2048;
    #pragma unroll
    for (int it = 0; it < 8; ++it)
        smemA[t + it * 256] = cfrag[abase + t + it * 256];
    __syncthreads();

    const int wave = t >> 6;
    const int lane = t & 63;
    const int wr   = wave >> 1;    // 0..1: which 64-row half of i
    const int wc   = wave & 1;     // 0..1: which 64-col half of j
    const int lrow = lane & 15;
    const int quad = lane >> 4;

    const int i0 = ti * 128 + wr * 64;

    // sq[i] values: fixed for the whole sweep
    floatx4 sqi[4];
    #pragma unroll
    for (int mt = 0; mt < 4; ++mt)
        sqi[mt] = *(const floatx4*)(sq + i0 + mt * 16 + quad * 4);

    float hsum = 0.f;

    for (int tj = tj0; tj < tjend; ++tj) {
        const bool bdiag = (tj == ti);
        if (bdiag && wr > wc) continue;      // wave-uniform skip (i>j always)

        const int j0 = tj * 128 + wc * 64;

        float sqj[4];
        #pragma unroll
        for (int nt = 0; nt < 4; ++nt)
            sqj[nt] = sq[j0 + nt * 16 + lrow];

        // B granule index for (col-group, k-batch): contiguous across wave
        #define BIDX(nt, ks) (((size_t)tj * 8 + wc * 4 + (nt)) * 256 + ((ks) * 4 + quad) * 16 + lrow)

        bf16x8 bb[2][4];
        #pragma unroll
        for (int pb = 0; pb < 2; ++pb)
            #pragma unroll
            for (int nt = 0; nt < 4; ++nt)
                bb[pb][nt] = __builtin_bit_cast(bf16x8, cfrag[BIDX(nt, pb)]);

        floatx4 c4[4][4] = {};

        #pragma unroll
        for (int ks = 0; ks < 4; ++ks) {         // K = 128, 32 per MFMA
            const int cur = ks & 1;
            bf16x8 a[4];
            const int go = (ks * 4 + quad) * 16 + lrow;
            #pragma unroll
            for (int mt = 0; mt < 4; ++mt)
                a[mt] = __builtin_bit_cast(bf16x8, smemA[(wr * 4 + mt) * 256 + go]);
            #pragma unroll
            for (int mt = 0; mt < 4; ++mt)
                #pragma unroll
                for (int nt = 0; nt < 4; ++nt)
                    c4[mt][nt] = __builtin_amdgcn_mfma_f32_16x16x32_bf16(
                                    a[mt], bb[cur][nt], c4[mt][nt], 0, 0, 0);
            if (ks < 2) {                        // refill with batch ks+2
                #pragma unroll
                for (int nt = 0; nt < 4; ++nt)
                    bb[cur][nt] = __builtin_bit_cast(bf16x8, cfrag[BIDX(nt, ks + 2)]);
            }
        }
        #undef BIDX

        // Epilogue: d2 = sq[i]+sq[j]-2*gram; hinge nonzero only when d2 < 1.
        const bool qdiag = (bdiag && wr == wc);
        #pragma unroll
        for (int mt = 0; mt < 4; ++mt) {
            #pragma unroll
            for (int nt = 0; nt < 4; ++nt) {
                const int ib = i0 + mt * 16 + quad * 4;
                const int j  = j0 + nt * 16 + lrow;
                #pragma unroll
                for (int r = 0; r < 4; ++r) {
                    if (qdiag && j <= ib + r) continue;
                    float d2 = sqi[mt][r] + sqj[nt] - 2.0f * c4[mt][nt][r];
                    if (d2 < 1.0f) {             // rare path
                        float d = sqrtf(fmaxf(d2, 0.f));
                        float tt = 1.0f - d;
                        hsum += tt * tt;
                    }
                }
            }
        }
    }

    if (__ballot(hsum != 0.f)) {
        hsum = wave_red64(hsum);
        if (lane == 0) atomicAdd(acc, hsum);
    }
}

// ---------------------------------------------------------------------------
// K3: reduce K1 partials, finalize both outputs.
// ---------------------------------------------------------------------------
__global__ __launch_bounds__(256) void k_final(
    const float* __restrict__ acc,
    const float* __restrict__ partial,
    float* __restrict__ out)
{
    __shared__ float sh[4];
    float s = 0.f;
    for (int i = threadIdx.x; i < K1_BLOCKS; i += 256) s += partial[i];
    s = wave_red64(s);
    const int wave = threadIdx.x >> 6;
    const int lane = threadIdx.x & 63;
    if (lane == 0) sh[wave] = s;
    __syncthreads();
    if (threadIdx.x == 0) {
        const float n_pairs = (float)G_GROUPS * (float)(G_GROUPS - 1) * 0.5f;
        out[0] = acc[0] / n_pairs;                                 // inter
        out[1] = (sh[0] + sh[1] + sh[2] + sh[3]) / (float)B_ROWS;  // intra
    }
}

extern "C" void kernel_launch(void* const* d_in, const int* in_sizes, int n_in,
                              void* d_out, int out_size, void* d_ws, size_t ws_size,
                              hipStream_t stream) {
    const float* x = (const float*)d_in[0];
    float* out = (float*)d_out;

    // workspace layout
    float* acc     = (float*)d_ws;                          // 4 B
    float* partial = (float*)((char*)d_ws + 256);           // 8 KB
    float* sq      = (float*)((char*)d_ws + 16384);         // 32 KB
    uint2* cfrag   = (uint2*)((char*)d_ws + 65536);         // 2 MB bf16 centers

    k_center_intra<<<K1_BLOCKS, 256, 0, stream>>>(x, cfrag, sq, partial, acc);

    k_inter<<<NCHUNK, 256, 0, stream>>>((const u16x8*)cfrag, sq, acc);

    k_final<<<1, 256, 0, stream>>>(acc, partial, out);
}

// Round 7
// 112.528 us; speedup vs baseline: 1.0688x; 1.0442x over previous
//
#include <hip/hip_runtime.h>
#include <hip/hip_bf16.h>
#include <math.h>

// Problem constants (from reference): path_fea (131072, 64, 1, 1, 2) fp32
#define B_ROWS   131072
#define D_DIM    128          // 64 * 2
#define P_SAMP   16
#define G_GROUPS 8192         // B / P
#define T128     64           // 128-row tiles per dim (G / 128)
#define NTRI2    2080         // T128*(T128+1)/2 triangular block-tiles
#define K1_BLOCKS (G_GROUPS / 4)

typedef __bf16 bf16x8  __attribute__((ext_vector_type(8)));
typedef float  floatx4 __attribute__((ext_vector_type(4)));
typedef unsigned short u16x8 __attribute__((ext_vector_type(8)));

// Fragment-ordered center layout (written by K1, read by K2):
//   granule index = (row>>4)*256 + gg*16 + (row&15),  gg = k-octet 0..15
//   each granule = 8 bf16 (16 B). A 128-row panel = one CONTIGUOUS 32 KB
//   chunk -> coalesced staging / 1 KB contiguous wave fragment loads.

__device__ __forceinline__ float wave_red64(float v) {
    #pragma unroll
    for (int off = 32; off > 0; off >>= 1) v += __shfl_xor(v, off, 64);
    return v;
}

// ---------------------------------------------------------------------------
// K1: per-group centers (bf16, fragment layout) + |center|^2 + intra hinge.
// One wave per group; all global loads are 1KB-contiguous wave-loads.
// (unchanged this round for attribution)
// ---------------------------------------------------------------------------
__global__ __launch_bounds__(256) void k_center_intra(
    const float* __restrict__ x,            // [B, 128]
    uint2* __restrict__ cfrag,               // [G*32] 8B halves of granules
    float* __restrict__ sq,                  // [G]
    float* __restrict__ partial,             // [K1_BLOCKS] intra partials
    float* __restrict__ acc)                 // acc[0] zeroed here
{
    const int wave = threadIdx.x >> 6;
    const int lane = threadIdx.x & 63;
    const int half = lane >> 5;      // sample parity this lane owns
    const int c    = lane & 31;      // dim-quad index (4 dims per lane)
    const int g    = blockIdx.x * 4 + wave;

    if (blockIdx.x == 0 && threadIdx.x == 0) acc[0] = 0.f;   // K2's accumulator

    // sample s = 2*l + half, dims 4c..4c+3
    const float* base = x + (size_t)g * (P_SAMP * D_DIM) + half * D_DIM + c * 4;

    floatx4 v[8];
    #pragma unroll
    for (int l = 0; l < 8; ++l)
        v[l] = *(const floatx4*)(base + l * (2 * D_DIM));

    floatx4 cs = v[0];
    #pragma unroll
    for (int l = 1; l < 8; ++l) cs += v[l];
    #pragma unroll
    for (int k = 0; k < 4; ++k) cs[k] += __shfl_xor(cs[k], 32, 64);
    floatx4 ctr = cs * (1.0f / P_SAMP);

    // 9 parallel partial sums: 8 sample dists + center sq-norm
    float p[9];
    #pragma unroll
    for (int l = 0; l < 8; ++l) {
        floatx4 d = v[l] - ctr;
        p[l] = d[0]*d[0] + d[1]*d[1] + d[2]*d[2] + d[3]*d[3];
    }
    p[8] = ctr[0]*ctr[0] + ctr[1]*ctr[1] + ctr[2]*ctr[2] + ctr[3]*ctr[3];

    #pragma unroll
    for (int off = 16; off > 0; off >>= 1) {
        #pragma unroll
        for (int s = 0; s < 9; ++s) p[s] += __shfl_xor(p[s], off, 64);
    }

    // store bf16 center into fragment layout (8 B per lane, half 0 only)
    if (half == 0) {
        unsigned int b0 = __builtin_bit_cast(unsigned short, (__bf16)ctr[0]);
        unsigned int b1 = __builtin_bit_cast(unsigned short, (__bf16)ctr[1]);
        unsigned int b2 = __builtin_bit_cast(unsigned short, (__bf16)ctr[2]);
        unsigned int b3 = __builtin_bit_cast(unsigned short, (__bf16)ctr[3]);
        uint2 pk;
        pk.x = (b1 << 16) | b0;
        pk.y = (b3 << 16) | b2;
        const int gran = (g >> 4) * 256 + (c >> 1) * 16 + (g & 15);
        cfrag[gran * 2 + (c & 1)] = pk;
    }
    if (lane == 0) sq[g] = p[8];

    float isum = 0.f;
    #pragma unroll
    for (int l = 0; l < 8; ++l) {
        float d = sqrtf(p[l]);
        float t = fmaxf(d - 0.1f, 0.f);
        isum += t * t;
    }
    isum += __shfl_xor(isum, 32, 64);

    __shared__ float sh[4];
    if (lane == 0) sh[wave] = isum;
    __syncthreads();
    if (threadIdx.x == 0)
        partial[blockIdx.x] = sh[0] + sh[1] + sh[2] + sh[3];
}

// ---------------------------------------------------------------------------
// K2: inter hinge. One BLOCK per 128x128 triangular tile (2080 blocks);
// 4 waves = 64x64 quadrants. A panel (contiguous 32 KB) staged to LDS once;
// B fragments stream direct-to-register (contiguous 1 KB wave-loads,
// k-batch double-buffered) — batches 0/1 and sq values issued BEFORE the
// staging barrier so they fly during the A stage. 32 KB LDS + VGPR cap at
// 3 waves/EU -> ~3 blocks/CU (~12 waves/CU): concurrency AND low traffic
// (133 MB total vs R4's 264 MB), the combination R4-R6 each lacked.
// ---------------------------------------------------------------------------
__global__ __launch_bounds__(256, 3) void k_inter(
    const u16x8* __restrict__ cfrag,         // granule array (16 B each)
    const float* __restrict__ sq,            // [G]
    float* __restrict__ acc)                 // acc[0] = inter hinge sum
{
    __shared__ u16x8 smemA[2048];   // 32 KB: A panel, fragment order

    // triangular decode over T128=64: off(i) = 64i - i(i-1)/2
    const int bid = blockIdx.x;
    float sf = sqrtf(64.5f * 64.5f - 2.0f * (float)bid);
    int ti = (int)(64.5f - sf);
    if (ti < 0) ti = 0;
    if (ti > T128 - 1) ti = T128 - 1;
    #define TRI_OFF(i) ((i) * T128 - (((i) * ((i) - 1)) >> 1))
    while (ti > 0 && TRI_OFF(ti) > bid) --ti;
    while (ti < T128 - 1 && TRI_OFF(ti + 1) <= bid) ++ti;
    const int tj = ti + (bid - TRI_OFF(ti));
    #undef TRI_OFF

    const int t    = threadIdx.x;
    const int wave = t >> 6;
    const int lane = t & 63;
    const int wr   = wave >> 1;    // 0..1: which 64-row half of i
    const int wc   = wave & 1;     // 0..1: which 64-col half of j
    const int lrow = lane & 15;
    const int quad = lane >> 4;

    const int i0 = ti * 128 + wr * 64;
    const int j0 = tj * 128 + wc * 64;

    // ---- issue B batches 0/1 + sq loads FIRST (independent of LDS) ----
    // B granule index for (col-group nt, k-batch ks): contiguous across wave
    #define BIDX(nt, ks) (((size_t)tj * 8 + wc * 4 + (nt)) * 256 + ((ks) * 4 + quad) * 16 + lrow)
    bf16x8 bb[2][4];
    #pragma unroll
    for (int pb = 0; pb < 2; ++pb)
        #pragma unroll
        for (int nt = 0; nt < 4; ++nt)
            bb[pb][nt] = __builtin_bit_cast(bf16x8, cfrag[BIDX(nt, pb)]);

    floatx4 sqi[4];
    float   sqj[4];
    #pragma unroll
    for (int mt = 0; mt < 4; ++mt)
        sqi[mt] = *(const floatx4*)(sq + i0 + mt * 16 + quad * 4);
    #pragma unroll
    for (int nt = 0; nt < 4; ++nt)
        sqj[nt] = sq[j0 + nt * 16 + lrow];

    // ---- stage A panel (rows ti*128..+128): one contiguous 32 KB chunk ----
    const size_t abase = (size_t)ti * 2048;
    #pragma unroll
    for (int it = 0; it < 8; ++it)
        smemA[t + it * 256] = cfrag[abase + t + it * 256];
    __syncthreads();

    const bool bdiag = (ti == tj);
    if (bdiag && wr > wc) return;            // strictly-lower quadrant (i>j)

    floatx4 c4[4][4] = {};   // 16 accumulator tiles of 16x16

    #pragma unroll
    for (int ks = 0; ks < 4; ++ks) {         // K = 128, 32 per MFMA
        const int cur = ks & 1;
        bf16x8 a[4];
        const int go = (ks * 4 + quad) * 16 + lrow;
        #pragma unroll
        for (int mt = 0; mt < 4; ++mt)
            a[mt] = __builtin_bit_cast(bf16x8, smemA[(wr * 4 + mt) * 256 + go]);
        #pragma unroll
        for (int mt = 0; mt < 4; ++mt)
            #pragma unroll
            for (int nt = 0; nt < 4; ++nt)
                c4[mt][nt] = __builtin_amdgcn_mfma_f32_16x16x32_bf16(
                                a[mt], bb[cur][nt], c4[mt][nt], 0, 0, 0);
        if (ks < 2) {                        // refill with batch ks+2
            #pragma unroll
            for (int nt = 0; nt < 4; ++nt)
                bb[cur][nt] = __builtin_bit_cast(bf16x8, cfrag[BIDX(nt, ks + 2)]);
        }
    }
    #undef BIDX

    // Epilogue: d2 = sq[i]+sq[j]-2*gram; hinge nonzero only when d2 < 1.
    const bool qdiag = (bdiag && wr == wc);
    float hsum = 0.f;
    #pragma unroll
    for (int mt = 0; mt < 4; ++mt) {
        #pragma unroll
        for (int nt = 0; nt < 4; ++nt) {
            const int ib = i0 + mt * 16 + quad * 4;
            const int j  = j0 + nt * 16 + lrow;
            #pragma unroll
            for (int r = 0; r < 4; ++r) {
                if (qdiag && j <= ib + r) continue;
                float d2 = sqi[mt][r] + sqj[nt] - 2.0f * c4[mt][nt][r];
                if (d2 < 1.0f) {             // rare path
                    float d = sqrtf(fmaxf(d2, 0.f));
                    float tt = 1.0f - d;
                    hsum += tt * tt;
                }
            }
        }
    }
    if (__ballot(hsum != 0.f)) {
        hsum = wave_red64(hsum);
        if (lane == 0) atomicAdd(acc, hsum);
    }
}

// ---------------------------------------------------------------------------
// K3: reduce K1 partials, finalize both outputs.
// ---------------------------------------------------------------------------
__global__ __launch_bounds__(256) void k_final(
    const float* __restrict__ acc,
    const float* __restrict__ partial,
    float* __restrict__ out)
{
    __shared__ float sh[4];
    float s = 0.f;
    for (int i = threadIdx.x; i < K1_BLOCKS; i += 256) s += partial[i];
    s = wave_red64(s);
    const int wave = threadIdx.x >> 6;
    const int lane = threadIdx.x & 63;
    if (lane == 0) sh[wave] = s;
    __syncthreads();
    if (threadIdx.x == 0) {
        const float n_pairs = (float)G_GROUPS * (float)(G_GROUPS - 1) * 0.5f;
        out[0] = acc[0] / n_pairs;                                 // inter
        out[1] = (sh[0] + sh[1] + sh[2] + sh[3]) / (float)B_ROWS;  // intra
    }
}

extern "C" void kernel_launch(void* const* d_in, const int* in_sizes, int n_in,
                              void* d_out, int out_size, void* d_ws, size_t ws_size,
                              hipStream_t stream) {
    const float* x = (const float*)d_in[0];
    float* out = (float*)d_out;

    // workspace layout
    float* acc     = (float*)d_ws;                          // 4 B
    float* partial = (float*)((char*)d_ws + 256);           // 8 KB
    float* sq      = (float*)((char*)d_ws + 16384);         // 32 KB
    uint2* cfrag   = (uint2*)((char*)d_ws + 65536);         // 2 MB bf16 centers

    k_center_intra<<<K1_BLOCKS, 256, 0, stream>>>(x, cfrag, sq, partial, acc);

    k_inter<<<NTRI2, 256, 0, stream>>>((const u16x8*)cfrag, sq, acc);

    k_final<<<1, 256, 0, stream>>>(acc, partial, out);
}